// Round 6
// baseline (142.439 us; speedup 1.0000x reference)
//
#include <hip/hip_runtime.h>
#include <math.h>

#define SS 8192
#define HH 2048
#define NBLK 256
#define NTHR 512

// Persistent coherent scratch (device globals: never poisoned by harness,
// never touched by plain cached loads/stores -> no stale-L2 hazard).
// All cross-block data moves through agent-scope atomics, which execute at
// the coherent point and bypass the non-coherent per-XCD L2s.
__device__ unsigned g_ctr = 0;                  // monotone barrier arrivals
__device__ unsigned g_rel = 0;                  // monotone release epoch
__device__ float g_part[NBLK][HH];              // per-block colsum partials
__device__ float g_v2[HH];                      // reduced v2 (fully rewritten each launch)
__device__ unsigned long long g_pair[NBLK];     // packed (m_b, s_b) per block

// Fence-free grid barrier (validated R5: dropped the buffer_wbl2/buffer_inv
// storm that cost ~50us/barrier). __syncthreads() drains vmcnt per wave, so
// every prior atomic is retired at the coherent point before the leader's
// fetch_add; any coherent read after the barrier must observe it.
// Pollers spin on g_rel (single-writer) so poll traffic doesn't contend
// with the arrival fetch_adds on g_ctr.
// Deadlock-safe: 256 blocks, __launch_bounds__(512,2) -> >=1 block/CU on
// 256 CUs -> all blocks co-resident.
__device__ __forceinline__ void grid_barrier() {
    __syncthreads();
    if (threadIdx.x == 0) {
        unsigned old = __hip_atomic_fetch_add(&g_ctr, 1u, __ATOMIC_RELAXED,
                                              __HIP_MEMORY_SCOPE_AGENT);
        unsigned epoch = old / NBLK;
        if (old % NBLK == NBLK - 1u) {
            __hip_atomic_store(&g_rel, epoch + 1u, __ATOMIC_RELAXED,
                               __HIP_MEMORY_SCOPE_AGENT);
        } else {
            while (__hip_atomic_load(&g_rel, __ATOMIC_RELAXED,
                                     __HIP_MEMORY_SCOPE_AGENT) <= epoch)
                __builtin_amdgcn_s_sleep(8);
        }
    }
    asm volatile("" ::: "memory");   // compiler-only ordering
    __syncthreads();
}

__global__ __launch_bounds__(NTHR, 2) void fused_kernel(
    const float* __restrict__ enc,
    const float* __restrict__ W,
    const float* __restrict__ w,
    float* __restrict__ out)
{
    const int b    = blockIdx.x;
    const int t    = threadIdx.x;
    const int wave = t >> 6;
    const int lane = t & 63;

    __shared__ float v2s[HH];        // 8 KB
    __shared__ float srow[32];       // this block's raw scores
    __shared__ float mv[NBLK];       // pair maxes
    __shared__ float sv[NBLK];       // pair sums
    __shared__ float red[2];

    // ---- Phase 1: partial colsum. Block b: rows 8b..8b+7, all 2048 cols
    // (512 thr x float4). Full-GPU 16 MB stream; contention-free atomic
    // stores of the partial (no atomicAdd chains). ----
    {
        const int row0 = b * 8;
        const float4* base =
            (const float4*)(W + (size_t)row0 * (2 * HH) + HH) + t;
        float4 acc = {0.f, 0.f, 0.f, 0.f};
#pragma unroll
        for (int j = 0; j < 8; ++j) {
            float4 a = base[(size_t)j * ((2 * HH) / 4)];
            float wj = w[row0 + j];              // block-uniform -> s_load
            acc.x += wj * a.x; acc.y += wj * a.y;
            acc.z += wj * a.z; acc.w += wj * a.w;
        }
        float* dst = &g_part[b][t * 4];
        __hip_atomic_store(dst + 0, acc.x, __ATOMIC_RELAXED, __HIP_MEMORY_SCOPE_AGENT);
        __hip_atomic_store(dst + 1, acc.y, __ATOMIC_RELAXED, __HIP_MEMORY_SCOPE_AGENT);
        __hip_atomic_store(dst + 2, acc.z, __ATOMIC_RELAXED, __HIP_MEMORY_SCOPE_AGENT);
        __hip_atomic_store(dst + 3, acc.w, __ATOMIC_RELAXED, __HIP_MEMORY_SCOPE_AGENT);
    }

    grid_barrier();

    // ---- Phase 1b: owner reduce. Wave `wave` of block b owns column
    // c = 8b+wave: sum g_part[0..255][c] (4 coherent loads/lane), wave
    // shfl-reduce, atomic-store g_v2[c]. 256 blocks x 8 waves = 2048 cols.
    {
        const int c = b * 8 + wave;
        float s = 0.0f;
#pragma unroll
        for (int k = 0; k < 4; ++k)
            s += __hip_atomic_load(&g_part[lane + k * 64][c],
                                   __ATOMIC_RELAXED, __HIP_MEMORY_SCOPE_AGENT);
#pragma unroll
        for (int off = 32; off > 0; off >>= 1)
            s += __shfl_down(s, off);
        if (lane == 0)
            __hip_atomic_store(&g_v2[c], s, __ATOMIC_RELAXED,
                               __HIP_MEMORY_SCOPE_AGENT);
    }

    grid_barrier();

    // ---- Phase 2: rowdot. v2 -> LDS (coherent), then 8 waves x 4 rows;
    // per-block (m_b, sumexp_b) published as one packed u64. ----
#pragma unroll
    for (int k = 0; k < 4; ++k)
        v2s[t + k * 512] = __hip_atomic_load(&g_v2[t + k * 512],
                                             __ATOMIC_RELAXED,
                                             __HIP_MEMORY_SCOPE_AGENT);
    __syncthreads();
    {
        const float4* v4 = (const float4*)v2s;
        float4 vf[8];
#pragma unroll
        for (int i = 0; i < 8; ++i) vf[i] = v4[lane + i * 64];

        const int row_base = b * 32 + wave * 4;
#pragma unroll
        for (int rr = 0; rr < 4; ++rr) {
            const int row = row_base + rr;
            const float4* e = (const float4*)(enc + (size_t)row * HH);
            float acc = 0.0f;
#pragma unroll
            for (int i = 0; i < 8; ++i) {
                float4 a = e[lane + i * 64];
                acc += a.x * vf[i].x + a.y * vf[i].y
                     + a.z * vf[i].z + a.w * vf[i].w;
            }
#pragma unroll
            for (int off = 32; off > 0; off >>= 1)
                acc += __shfl_down(acc, off);
            if (lane == 0) srow[wave * 4 + rr] = acc;
        }
    }
    __syncthreads();

    if (wave == 0) {
        float v = (lane < 32) ? srow[lane] : -INFINITY;
        float m = v;
#pragma unroll
        for (int off = 1; off < 64; off <<= 1)
            m = fmaxf(m, __shfl_xor(m, off));
        float s = (lane < 32) ? __expf(v - m) : 0.0f;
#pragma unroll
        for (int off = 1; off < 64; off <<= 1)
            s += __shfl_xor(s, off);
        if (lane == 0) {
            unsigned long long p =
                ((unsigned long long)__float_as_uint(s) << 32) |
                (unsigned long long)__float_as_uint(m);
            __hip_atomic_store(&g_pair[b], p, __ATOMIC_RELAXED,
                               __HIP_MEMORY_SCOPE_AGENT);
        }
    }

    grid_barrier();

    // ---- Phase 3: combine 256 pairs (2 KB coherent reads), write own
    // 32-element output slice from srow (still in LDS). ----
    if (t < NBLK) {
        unsigned long long p = __hip_atomic_load(&g_pair[t], __ATOMIC_RELAXED,
                                                 __HIP_MEMORY_SCOPE_AGENT);
        mv[t] = __uint_as_float((unsigned)(p & 0xffffffffu));
        sv[t] = __uint_as_float((unsigned)(p >> 32));
    }
    __syncthreads();
    if (wave == 0) {
        float m4 = fmaxf(fmaxf(mv[lane], mv[lane + 64]),
                         fmaxf(mv[lane + 128], mv[lane + 192]));
#pragma unroll
        for (int off = 32; off > 0; off >>= 1)
            m4 = fmaxf(m4, __shfl_xor(m4, off));
        if (lane == 0) red[0] = m4;
    }
    __syncthreads();
    const float M = red[0];
    if (wave == 0) {
        float s4 = sv[lane]       * __expf(mv[lane]       - M)
                 + sv[lane + 64]  * __expf(mv[lane + 64]  - M)
                 + sv[lane + 128] * __expf(mv[lane + 128] - M)
                 + sv[lane + 192] * __expf(mv[lane + 192] - M);
#pragma unroll
        for (int off = 32; off > 0; off >>= 1)
            s4 += __shfl_xor(s4, off);
        if (lane == 0) red[1] = s4;
    }
    __syncthreads();
    const float inv = 1.0f / red[1];

    if (t < 32)
        out[b * 32 + t] = __expf(srow[t] - M) * inv;
}

extern "C" void kernel_launch(void* const* d_in, const int* in_sizes, int n_in,
                              void* d_out, int out_size, void* d_ws, size_t ws_size,
                              hipStream_t stream) {
    const float* enc   = (const float*)d_in[0];  // (S,1,H) -> (S,H)
    // d_in[1] = hidden : constant score shift -> cancels in softmax
    const float* W_att = (const float*)d_in[2];  // (H, 2H)
    // d_in[3] = b_att  : constant shift -> cancels
    const float* w     = (const float*)d_in[4];  // (1, H)

    float* out = (float*)d_out;                  // 8192 floats (1,1,S)

    hipLaunchKernelGGL(fused_kernel, dim3(NBLK), dim3(NTHR), 0, stream,
                       enc, W_att, w, out);
}

// Round 7
// 138.072 us; speedup vs baseline: 1.0316x; 1.0316x over previous
//
#include <hip/hip_runtime.h>
#include <math.h>

#define SS 8192
#define HH 2048
#define NBLK 256
#define NTHR 512
#define NP 4

// Persistent coherent scratch. All cross-block data moves via agent-scope
// atomics (coherent point, bypasses non-coherent per-XCD L2s) -> no fences
// needed (validated R5: fence version cost ~50us/barrier, fence-free ~5).
// g_part is parity double-buffered: launch L accumulates into bank L&1 and
// re-zeroes it after use; bank (L+1)&1 was zeroed by launch L-1 (bank 0/1
// both zero at module load). Parity is read from the quiescent barrier
// counter at kernel entry (stable between launches: = launches*2*NBLK).
__device__ unsigned g_ctr = 0;                    // monotone barrier arrivals
__device__ unsigned g_rel = 0;                    // monotone release epoch
__device__ float g_part[2][NP][HH] = {};          // colsum partial banks
__device__ unsigned long long g_pair[NBLK];       // packed (m_b, s_b)

// Fence-free grid barrier (R5-validated). __syncthreads() drains vmcnt per
// wave, so prior atomics are retired at the coherent point before the
// leader's fetch_add; coherent reads after the barrier must observe them.
// Deadlock-safe: 256 blocks, >=1 block/CU on 256 CUs -> all co-resident.
__device__ __forceinline__ void grid_barrier() {
    __syncthreads();
    if (threadIdx.x == 0) {
        unsigned old = __hip_atomic_fetch_add(&g_ctr, 1u, __ATOMIC_RELAXED,
                                              __HIP_MEMORY_SCOPE_AGENT);
        unsigned epoch = old / NBLK;
        if (old % NBLK == NBLK - 1u) {
            __hip_atomic_store(&g_rel, epoch + 1u, __ATOMIC_RELAXED,
                               __HIP_MEMORY_SCOPE_AGENT);
        } else {
            while (__hip_atomic_load(&g_rel, __ATOMIC_RELAXED,
                                     __HIP_MEMORY_SCOPE_AGENT) <= epoch)
                __builtin_amdgcn_s_sleep(8);
        }
    }
    asm volatile("" ::: "memory");   // compiler-only ordering
    __syncthreads();
}

__global__ __launch_bounds__(NTHR, 2) void fused_kernel(
    const float* __restrict__ enc,
    const float* __restrict__ W,
    const float* __restrict__ w,
    float* __restrict__ out)
{
    const int b    = blockIdx.x;
    const int t    = threadIdx.x;
    const int wave = t >> 6;
    const int lane = t & 63;

    __shared__ float v2s[HH];        // 8 KB reduced v2
    __shared__ float srow[32];       // this block's raw scores
    __shared__ float mv[NBLK];       // pair maxes
    __shared__ float sv[NBLK];       // pair sums
    __shared__ float red[2];
    __shared__ unsigned sh_par;

    if (t == 0) {
        unsigned c = __hip_atomic_load(&g_ctr, __ATOMIC_RELAXED,
                                       __HIP_MEMORY_SCOPE_AGENT);
        sh_par = (c / (2u * NBLK)) & 1u;
    }
    __syncthreads();
    const unsigned par = sh_par;

    // ---- Issue ALL memory up front: 8 W float4 (phase 1) then 32 enc
    // float4 (this wave's 4 phase-2 rows). 40 outstanding 16B loads/lane
    // = 320 KB in flight/CU -> the full 80 MB payload streams at near-peak
    // BW while phase 1 computes and barrier 1 drains. ----
    const int row0 = b * 8;
    const float4* wbase =
        (const float4*)(W + (size_t)row0 * (2 * HH) + HH) + t;
    float4 wv[8];
#pragma unroll
    for (int j = 0; j < 8; ++j)
        wv[j] = wbase[(size_t)j * ((2 * HH) / 4)];

    const int rbase = b * 32 + wave * 4;
    float4 er[4][8];
#pragma unroll
    for (int rr = 0; rr < 4; ++rr) {
        const float4* e = (const float4*)(enc + (size_t)(rbase + rr) * HH);
#pragma unroll
        for (int i = 0; i < 8; ++i)
            er[rr][i] = e[lane + i * 64];
    }

    // ---- Phase 1: colsum partial. Block b: rows 8b..8b+7, all 2048 cols.
    // atomicAdd into bank `par`, sub-bank b&3 -> 64 adds/address (R5-proven
    // contention level). ----
    {
        float4 acc = {0.f, 0.f, 0.f, 0.f};
#pragma unroll
        for (int j = 0; j < 8; ++j) {
            float wj = w[row0 + j];              // block-uniform -> s_load
            acc.x += wj * wv[j].x; acc.y += wj * wv[j].y;
            acc.z += wj * wv[j].z; acc.w += wj * wv[j].w;
        }
        float* dst = &g_part[par][b & 3][t * 4];
        atomicAdd(dst + 0, acc.x);
        atomicAdd(dst + 1, acc.y);
        atomicAdd(dst + 2, acc.z);
        atomicAdd(dst + 3, acc.w);
    }

    grid_barrier();

    // ---- Phase 2a: v2 -> LDS. 16 coherent loads/thread, all wave-coalesced
    // (consecutive t -> consecutive addresses within each sub-bank; R6's
    // regression was lane-strided coherent loads - never again). ----
#pragma unroll
    for (int k = 0; k < 4; ++k) {
        const int c = t + k * 512;
        float s = 0.0f;
#pragma unroll
        for (int p = 0; p < NP; ++p)
            s += __hip_atomic_load(&g_part[par][p][c], __ATOMIC_RELAXED,
                                   __HIP_MEMORY_SCOPE_AGENT);
        v2s[c] = s;
    }
    __syncthreads();

    // ---- Phase 2b: rowdot from register-held enc (pure ALU now). ----
    {
        const float4* v4 = (const float4*)v2s;
        float4 vf[8];
#pragma unroll
        for (int i = 0; i < 8; ++i) vf[i] = v4[lane + i * 64];

#pragma unroll
        for (int rr = 0; rr < 4; ++rr) {
            float acc = 0.0f;
#pragma unroll
            for (int i = 0; i < 8; ++i) {
                acc += er[rr][i].x * vf[i].x + er[rr][i].y * vf[i].y
                     + er[rr][i].z * vf[i].z + er[rr][i].w * vf[i].w;
            }
#pragma unroll
            for (int off = 32; off > 0; off >>= 1)
                acc += __shfl_down(acc, off);
            if (lane == 0) srow[wave * 4 + rr] = acc;
        }
    }
    __syncthreads();

    // ---- Publish per-block (max, sumexp) pair. ----
    if (wave == 0) {
        float v = (lane < 32) ? srow[lane] : -INFINITY;
        float m = v;
#pragma unroll
        for (int off = 1; off < 64; off <<= 1)
            m = fmaxf(m, __shfl_xor(m, off));
        float s = (lane < 32) ? __expf(v - m) : 0.0f;
#pragma unroll
        for (int off = 1; off < 64; off <<= 1)
            s += __shfl_xor(s, off);
        if (lane == 0) {
            unsigned long long p =
                ((unsigned long long)__float_as_uint(s) << 32) |
                (unsigned long long)__float_as_uint(m);
            __hip_atomic_store(&g_pair[b], p, __ATOMIC_RELAXED,
                               __HIP_MEMORY_SCOPE_AGENT);
        }
    }

    grid_barrier();

    // ---- Re-zero own slice of bank `par` (nobody reads it after barrier
    // 2; next launch uses the other bank). 32 atomic stores/block. ----
    if (t < 32) {
        const int idx = b * 32 + t;
        __hip_atomic_store(&g_part[par][idx >> 11][idx & 2047], 0.0f,
                           __ATOMIC_RELAXED, __HIP_MEMORY_SCOPE_AGENT);
    }

    // ---- Phase 3: combine 256 pairs (coalesced coherent loads), write
    // own 32-element output slice from srow (still in LDS). ----
    if (t < NBLK) {
        unsigned long long p = __hip_atomic_load(&g_pair[t], __ATOMIC_RELAXED,
                                                 __HIP_MEMORY_SCOPE_AGENT);
        mv[t] = __uint_as_float((unsigned)(p & 0xffffffffu));
        sv[t] = __uint_as_float((unsigned)(p >> 32));
    }
    __syncthreads();
    if (wave == 0) {
        float m4 = fmaxf(fmaxf(mv[lane], mv[lane + 64]),
                         fmaxf(mv[lane + 128], mv[lane + 192]));
#pragma unroll
        for (int off = 32; off > 0; off >>= 1)
            m4 = fmaxf(m4, __shfl_xor(m4, off));
        if (lane == 0) red[0] = m4;
    }
    __syncthreads();
    const float M = red[0];
    if (wave == 0) {
        float s4 = sv[lane]       * __expf(mv[lane]       - M)
                 + sv[lane + 64]  * __expf(mv[lane + 64]  - M)
                 + sv[lane + 128] * __expf(mv[lane + 128] - M)
                 + sv[lane + 192] * __expf(mv[lane + 192] - M);
#pragma unroll
        for (int off = 32; off > 0; off >>= 1)
            s4 += __shfl_xor(s4, off);
        if (lane == 0) red[1] = s4;
    }
    __syncthreads();
    const float inv = 1.0f / red[1];

    if (t < 32)
        out[b * 32 + t] = __expf(srow[t] - M) * inv;
}

extern "C" void kernel_launch(void* const* d_in, const int* in_sizes, int n_in,
                              void* d_out, int out_size, void* d_ws, size_t ws_size,
                              hipStream_t stream) {
    const float* enc   = (const float*)d_in[0];  // (S,1,H) -> (S,H)
    // d_in[1] = hidden : constant score shift -> cancels in softmax
    const float* W_att = (const float*)d_in[2];  // (H, 2H)
    // d_in[3] = b_att  : constant shift -> cancels
    const float* w     = (const float*)d_in[4];  // (1, H)

    float* out = (float*)d_out;                  // 8192 floats (1,1,S)

    hipLaunchKernelGGL(fused_kernel, dim3(NBLK), dim3(NTHR), 0, stream,
                       enc, W_att, w, out);
}